// Round 4
// baseline (267.335 us; speedup 1.0000x reference)
//
#include <hip/hip_runtime.h>
#include <hip/hip_bf16.h>
#include <math.h>

#define BB 8
#define NN 2048
#define WWID 64
#define RNUM 4
#define CTRL 272      // R*W + R + R*3
#define EPSF 1e-8f

typedef __attribute__((ext_vector_type(8))) short short8v;   // 8 bf16 (4 VGPR)
typedef __attribute__((ext_vector_type(4))) float f32x4;
typedef __attribute__((ext_vector_type(2))) int int2v;

__device__ __forceinline__ float wred_sum(float v){
#pragma unroll
  for (int m=1;m<64;m<<=1) v += __shfl_xor(v,m);
  return v;
}

__device__ __forceinline__ short bf16c(float f){
  __hip_bfloat16 h = __float2bfloat16(f);
  return *reinterpret_cast<short*>(&h);
}

// K1: per (b,n) wave: scores[b,r,n] (beta folded), Ldiag[b,n]=L[b,n,n],
//     Xt[b][v][n] bf16: v<4: prw_r ; v=4..7: ww*prw_r ; v=8..15: 0
__global__ __launch_bounds__(256) void k1_prep(
    const float* __restrict__ mem, const float* __restrict__ ctr,
    const float* __restrict__ ww, const float* __restrict__ prw,
    const float* __restrict__ L,
    float* __restrict__ scores, float* __restrict__ Ldiag,
    unsigned short* __restrict__ Xt){
  int tid = threadIdx.x, wid = tid>>6, lane = tid&63;
  int g = blockIdx.x*4 + wid;            // g = b*NN + n
  int b = g >> 11, n = g & (NN-1);
  float m = mem[((size_t)g)*WWID + lane];
  const float* cb = ctr + b*CTRL;
  float k0 = cb[0*WWID+lane], k1 = cb[1*WWID+lane];
  float k2 = cb[2*WWID+lane], k3 = cb[3*WWID+lane];
  float s0 = m*m;
  float d0 = m*k0, d1 = m*k1, d2 = m*k2, d3 = m*k3;
  float q0 = k0*k0, q1 = k1*k1, q2 = k2*k2, q3 = k3*k3;
#pragma unroll
  for (int t=1;t<64;t<<=1){
    s0 += __shfl_xor(s0,t);
    d0 += __shfl_xor(d0,t); d1 += __shfl_xor(d1,t);
    d2 += __shfl_xor(d2,t); d3 += __shfl_xor(d3,t);
    q0 += __shfl_xor(q0,t); q1 += __shfl_xor(q1,t);
    q2 += __shfl_xor(q2,t); q3 += __shfl_xor(q3,t);
  }
  if (lane==0){
    float mn = sqrtf(s0);
    float be[4];
#pragma unroll
    for (int r=0;r<4;r++){
      float x = cb[RNUM*WWID + r];
      be[r] = 1.f + (x > 20.f ? x : log1pf(expf(x)));
    }
    scores[(b*RNUM+0)*NN+n] = d0*be[0]/(sqrtf(q0)*mn + EPSF);
    scores[(b*RNUM+1)*NN+n] = d1*be[1]/(sqrtf(q1)*mn + EPSF);
    scores[(b*RNUM+2)*NN+n] = d2*be[2]/(sqrtf(q2)*mn + EPSF);
    scores[(b*RNUM+3)*NN+n] = d3*be[3]/(sqrtf(q3)*mn + EPSF);
    Ldiag[b*NN+n] = L[((size_t)g)*NN + n];
  }
  if (tid < 64){
    int v = tid & 15, n4 = tid >> 4;
    int g2 = blockIdx.x*4 + n4;
    int b2 = g2>>11, n2 = g2&(NN-1);
    float val = 0.f;
    if (v < 4)      val = prw[((size_t)b2*RNUM+v)*NN + n2];
    else if (v < 8) val = ww[(size_t)b2*NN+n2] * prw[((size_t)b2*RNUM+(v-4))*NN + n2];
    Xt[((size_t)b2*16 + v)*NN + n2] = (unsigned short)bf16c(val);
  }
}

// K2: per (b,r): scalars {g0,g1,g2,S,T,invSum}.  No max-shift (|score|<~8).
__global__ __launch_bounds__(1024) void k2_head(
    const float* __restrict__ ctr, const float* __restrict__ scores,
    const float* __restrict__ ww, const float* __restrict__ prec,
    const float* __restrict__ prw, float* __restrict__ scal){
  __shared__ float redS[16], redT[16], redE[16];
  int tid=threadIdx.x, wid=tid>>6, lane=tid&63;
  int b = blockIdx.x>>2, r = blockIdx.x&3;
  const float* sc = scores + (size_t)(b*RNUM+r)*NN;
  const float* pr = prw    + (size_t)(b*RNUM+r)*NN;
  float s0=sc[tid], s1=sc[tid+1024];
  float p0=pr[tid], p1=pr[tid+1024];
  float lE = expf(s0)+expf(s1);
  float lS = prec[b*NN+tid]*p0 + prec[b*NN+tid+1024]*p1;
  float lT = ww[b*NN+tid]*p0   + ww[b*NN+tid+1024]*p1;
  lE=wred_sum(lE); lS=wred_sum(lS); lT=wred_sum(lT);
  if (lane==0){ redE[wid]=lE; redS[wid]=lS; redT[wid]=lT; }
  __syncthreads();
  if (tid==0){
    float S=0.f,T=0.f,E=0.f;
#pragma unroll
    for(int i=0;i<16;i++){ S+=redS[i]; T+=redT[i]; E+=redE[i]; }
    const float* cb = ctr + b*CTRL;
    float c0 = cb[RNUM*WWID + RNUM + r*3 + 0];
    float c1 = cb[RNUM*WWID + RNUM + r*3 + 1];
    float c2 = cb[RNUM*WWID + RNUM + r*3 + 2];
    float mg = fmaxf(c0, fmaxf(c1, c2));
    float e0 = expf(c0-mg), e1 = expf(c1-mg), e2 = expf(c2-mg);
    float inv3 = 1.f/(e0+e1+e2);
    float* s = &scal[(b*RNUM+r)*8];
    s[0]=e0*inv3; s[1]=e1*inv3; s[2]=e2*inv3;
    s[3]=S; s[4]=T; s[5]=1.f/E;
  }
}

// K3: MFMA streaming pass over L.  Block = 4 waves, 64 i-rows x 512 j-cols.
// Row side: ROW[i,v] += L(16x32) x X(32x16)  (A direct from global regs)
// Col side: COL[j,v] via A=Xt(16x32 over i), B=L(32 i x 16 j) from LDS tr-read
// LDS tile layout (bf16 elem idx): ((i>>2)*4 + (j>>4))*64 + (i&3)*16 + (j&15)
__global__ __launch_bounds__(256) void k3_links(
    const float* __restrict__ L, const unsigned short* __restrict__ Xt,
    float* __restrict__ fwd_part, float* __restrict__ part){
  __shared__ __attribute__((aligned(16))) unsigned short tile[4096]; // 64x64 bf16
  int tid = threadIdx.x, w = tid>>6, l = tid&63;
  int lrow = l & 15, lgrp = l >> 4;
  int bid = blockIdx.x;
  int b = bid >> 7;            // /128
  int rem = bid & 127;
  int ib = rem >> 2, jq = rem & 3;
  int i0 = ib*64, j0b = jq*512;

  const unsigned short* xb = Xt + (size_t)b*16*NN;
  // hoisted col-side A-frags (k = i-chunk), rows v>=8 are zero
  short8v afc0 = *(const short8v*)&xb[(size_t)lrow*NN + i0 +      lgrp*8];
  short8v afc1 = *(const short8v*)&xb[(size_t)lrow*NN + i0 + 32 + lgrp*8];

  f32x4 accRow = {0.f,0.f,0.f,0.f};
  int irel = w*16 + lrow;
  int wbase = (irel>>2)*256 + (irel&3)*16;          // element index base for writes
  unsigned lbase = (unsigned)(size_t)(&tile[0]) + (unsigned)(lgrp*1024 + w*128 + lrow*2);

  for (int sc=0; sc<8; ++sc){
    int j0 = j0b + sc*64;
    const float* Lr = L + ((size_t)(b*NN + i0 + w*16 + lrow))*NN + j0 + lgrp*8;
    f32x4 La0 = __builtin_nontemporal_load((const f32x4*)Lr);
    f32x4 La1 = __builtin_nontemporal_load((const f32x4*)(Lr+4));
    f32x4 Lb0 = __builtin_nontemporal_load((const f32x4*)(Lr+32));
    f32x4 Lb1 = __builtin_nontemporal_load((const f32x4*)(Lr+36));
    short8v a0, a1;
#pragma unroll
    for (int e=0;e<4;e++){ a0[e]=bf16c(La0[e]); a0[4+e]=bf16c(La1[e]); }
#pragma unroll
    for (int e=0;e<4;e++){ a1[e]=bf16c(Lb0[e]); a1[4+e]=bf16c(Lb1[e]); }

    __syncthreads();   // prior iteration's tr-reads done before overwrite
    int jr0 = lgrp*8;
    *(short8v*)&tile[wbase + (jr0>>4)*64 + (jr0&15)] = a0;
    int jr1 = 32 + lgrp*8;
    *(short8v*)&tile[wbase + (jr1>>4)*64 + (jr1&15)] = a1;
    __syncthreads();

    // row-side B-frags from Xt (k = j-chunk)
    short8v b0 = *(const short8v*)&xb[(size_t)lrow*NN + j0 +      lgrp*8];
    short8v b1 = *(const short8v*)&xb[(size_t)lrow*NN + j0 + 32 + lgrp*8];
    accRow = __builtin_amdgcn_mfma_f32_16x16x32_bf16(a0, b0, accRow, 0,0,0);
    accRow = __builtin_amdgcn_mfma_f32_16x16x32_bf16(a1, b1, accRow, 0,0,0);

    // col-side: wave w owns j-tile jt=w (j = j0 + w*16 + lrow)
    int2v t00,t01,t10,t11;
    asm volatile("ds_read_b64_tr_b16 %0, %1 offset:0"    : "=v"(t00) : "v"(lbase));
    asm volatile("ds_read_b64_tr_b16 %0, %1 offset:512"  : "=v"(t01) : "v"(lbase));
    asm volatile("ds_read_b64_tr_b16 %0, %1 offset:4096" : "=v"(t10) : "v"(lbase));
    asm volatile("ds_read_b64_tr_b16 %0, %1 offset:4608" : "=v"(t11) : "v"(lbase));
    asm volatile("s_waitcnt lgkmcnt(0)");
    __builtin_amdgcn_sched_barrier(0);
    union { int2v p[2]; short8v s; } bc0, bc1;
    bc0.p[0]=t00; bc0.p[1]=t01;
    bc1.p[0]=t10; bc1.p[1]=t11;
    f32x4 colD = {0.f,0.f,0.f,0.f};
    colD = __builtin_amdgcn_mfma_f32_16x16x32_bf16(afc0, bc0.s, colD, 0,0,0);
    colD = __builtin_amdgcn_mfma_f32_16x16x32_bf16(afc1, bc1.s, colD, 0,0,0);
    // store col partial: lanes l<32 hold v = lgrp*4+reg in 0..7, j = j0+w*16+lrow
    if (l < 32){
      int jabs = j0 + w*16 + lrow;
#pragma unroll
      for (int q=0;q<4;q++)
        part[((size_t)((b*32+ib)*8) + lgrp*4+q)*NN + jabs] = colD[q];
    }
  }
  // row partial: lane holds v = lrow (keep <8), i = i0+w*16+lgrp*4+reg
  if (lrow < 8){
    float* fp = fwd_part + ((size_t)((b*4+jq)*8) + lrow)*NN + i0 + w*16 + lgrp*4;
    *(f32x4*)fp = accRow;
  }
}

// K4: reduce partials + epilogue -> read_weights
__global__ __launch_bounds__(256) void k4_combine(
    const float* __restrict__ part, const float* __restrict__ fwd_part,
    const float* __restrict__ scores, const float* __restrict__ scal,
    const float* __restrict__ ww, const float* __restrict__ prec,
    const float* __restrict__ prw, const float* __restrict__ Ldiag,
    float* __restrict__ rw){
  int b = blockIdx.x >> 5, rem = blockIdx.x & 31;
  int r = rem >> 3, nb = rem & 7;
  int n = nb*256 + threadIdx.x;
  const float* s = &scal[(b*RNUM+r)*8];
  float g0=s[0], g1=s[1], g2=s[2], S=s[3], T=s[4], inv=s[5];
  float V=0.f, W=0.f;
#pragma unroll
  for (int jq=0;jq<4;jq++){
    V += fwd_part[((size_t)((b*4+jq)*8) + r  )*NN + n];
    W += fwd_part[((size_t)((b*4+jq)*8) + r+4)*NN + n];
  }
  float P=0.f, Q=0.f;
#pragma unroll 8
  for (int ib=0;ib<32;ib++){
    P += part[((size_t)((b*32+ib)*8) + r  )*NN + n];
    Q += part[((size_t)((b*32+ib)*8) + r+4)*NN + n];
  }
  float wwn = ww[b*NN+n], pn = prec[b*NN+n], prn = prw[(b*RNUM+r)*NN+n];
  float Lnn = Ldiag[b*NN+n];
  float diag = (fmaf(-2.f*wwn, Lnn, Lnn) + wwn*pn) * prn;
  float fwd = fmaf(1.f-wwn, V, -W) + wwn*S - diag;
  float bwd = fmaf(1.f-wwn, P, -Q) + pn*T - diag;
  float content = expf(scores[(b*RNUM+r)*NN+n]) * inv;
  rw[(b*RNUM+r)*NN+n] = g0*fwd + g1*bwd + g2*content;
}

// K5: out[b,r,w] = sum_n mem[b,n,w]*rw[b,r,n]  (block per (b,r), no atomics)
__global__ __launch_bounds__(256) void k5_read(
    const float* __restrict__ mem, const float* __restrict__ rw,
    float* __restrict__ out){
  __shared__ float rl[NN];
  __shared__ float red[4][WWID];
  int tid=threadIdx.x, w=tid>>6, lane=tid&63;
  int b = blockIdx.x>>2, r = blockIdx.x&3;
  const float* rp = rw + (size_t)(b*RNUM+r)*NN;
  { const f32x4* s4=(const f32x4*)rp; f32x4* d4=(f32x4*)rl;
    d4[tid] = s4[tid]; d4[tid+256] = s4[tid+256]; }
  __syncthreads();
  float acc = 0.f;
  const float* mp = mem + (size_t)b*NN*WWID + (size_t)w*512*WWID + lane;
#pragma unroll 4
  for (int k=0;k<512;k++)
    acc = fmaf(mp[(size_t)k*WWID], rl[w*512+k], acc);
  red[w][lane] = acc;
  __syncthreads();
  if (w==0)
    out[((size_t)(b*RNUM+r))*WWID + lane] =
      red[0][lane]+red[1][lane]+red[2][lane]+red[3][lane];
}

extern "C" void kernel_launch(void* const* d_in, const int* in_sizes, int n_in,
                              void* d_out, int out_size, void* d_ws, size_t ws_size,
                              hipStream_t stream){
  const float* mem  = (const float*)d_in[0];
  const float* ctr  = (const float*)d_in[1];
  const float* ww   = (const float*)d_in[2];
  const float* L    = (const float*)d_in[3];
  const float* prec = (const float*)d_in[4];
  const float* prw  = (const float*)d_in[5];
  float* out = (float*)d_out;
  float* w = (float*)d_ws;

  float* scores   = w;                               // B*R*N      = 65536
  float* Ldiag    = scores + BB*RNUM*NN;             // B*N        = 16384
  float* scal     = Ldiag + BB*NN;                   // 256
  float* rw       = scal + 256;                      // B*R*N
  float* fwd_part = rw + BB*RNUM*NN;                 // B*4*8*N    = 524288
  float* part     = fwd_part + BB*4*8*NN;            // B*32*8*N   = 4194304
  unsigned short* Xt = (unsigned short*)(part + (size_t)BB*32*8*NN); // B*16*N bf16

  k1_prep<<<BB*NN/4, 256, 0, stream>>>(mem, ctr, ww, prw, L, scores, Ldiag, Xt);
  k2_head<<<BB*RNUM, 1024, 0, stream>>>(ctr, scores, ww, prec, prw, scal);
  k3_links<<<BB*32*4, 256, 0, stream>>>(L, Xt, fwd_part, part);
  k4_combine<<<BB*RNUM*8, 256, 0, stream>>>(part, fwd_part, scores, scal, ww, prec, prw, Ldiag, rw);
  k5_read<<<BB*RNUM, 256, 0, stream>>>(mem, rw, out);
}

// Round 5
// 249.985 us; speedup vs baseline: 1.0694x; 1.0694x over previous
//
#include <hip/hip_runtime.h>
#include <math.h>

#define BB 8
#define NN 2048
#define WWID 64
#define RNUM 4
#define CTRL 272      // R*W + R + R*3
#define EPSF 1e-8f
#define TI 32         // rows per K3 block
#define TILES 64      // NN/TI
#define CQ 4          // column quarters in K3 (512 cols each)

__device__ __forceinline__ float wred_sum(float v){
#pragma unroll
  for (int m=1;m<64;m<<=1) v += __shfl_xor(v,m);
  return v;
}

// K1: per (b,n) wave: scores[b,r,n] (beta folded in), a[b,r,n]=(1-ww)*prw,
//     Ldiag[b,n] = L[b,n,n]
__global__ __launch_bounds__(256) void k1_prep(
    const float* __restrict__ mem, const float* __restrict__ ctr,
    const float* __restrict__ ww, const float* __restrict__ prw,
    const float* __restrict__ L,
    float* __restrict__ scores, float* __restrict__ a_arr,
    float* __restrict__ Ldiag){
  int wid = threadIdx.x >> 6, lane = threadIdx.x & 63;
  int g = blockIdx.x * 4 + wid;        // wave id == (b,n)
  int b = g >> 11, n = g & (NN-1);
  float m = mem[((size_t)(b*NN + n))*WWID + lane];
  const float* cb = ctr + b*CTRL;
  float k0 = cb[0*WWID+lane], k1 = cb[1*WWID+lane];
  float k2 = cb[2*WWID+lane], k3 = cb[3*WWID+lane];
  float s0 = m*m;
  float d0 = m*k0, d1 = m*k1, d2 = m*k2, d3 = m*k3;
  float q0 = k0*k0, q1 = k1*k1, q2 = k2*k2, q3 = k3*k3;
#pragma unroll
  for (int t=1;t<64;t<<=1){
    s0 += __shfl_xor(s0,t);
    d0 += __shfl_xor(d0,t); d1 += __shfl_xor(d1,t);
    d2 += __shfl_xor(d2,t); d3 += __shfl_xor(d3,t);
    q0 += __shfl_xor(q0,t); q1 += __shfl_xor(q1,t);
    q2 += __shfl_xor(q2,t); q3 += __shfl_xor(q3,t);
  }
  if (lane==0){
    float mn = sqrtf(s0);
    float be[4];
#pragma unroll
    for (int r=0;r<4;r++){
      float x = cb[RNUM*WWID + r];
      be[r] = 1.f + (x > 20.f ? x : log1pf(expf(x)));
    }
    scores[(b*RNUM+0)*NN+n] = d0*be[0]/(sqrtf(q0)*mn + EPSF);
    scores[(b*RNUM+1)*NN+n] = d1*be[1]/(sqrtf(q1)*mn + EPSF);
    scores[(b*RNUM+2)*NN+n] = d2*be[2]/(sqrtf(q2)*mn + EPSF);
    scores[(b*RNUM+3)*NN+n] = d3*be[3]/(sqrtf(q3)*mn + EPSF);
    Ldiag[b*NN+n] = L[((size_t)(b*NN+n))*NN + n];
  }
  if (lane < RNUM){
    int r = lane;
    a_arr[(b*RNUM+r)*NN+n] = (1.f - ww[b*NN+n]) * prw[(b*RNUM+r)*NN+n];
  }
}

// K2: per (b,r): scalars {g0,g1,g2,S,T,invSum}.  No max-shift (scores bounded).
__global__ __launch_bounds__(1024) void k2_head(
    const float* __restrict__ ctr, const float* __restrict__ scores,
    const float* __restrict__ ww, const float* __restrict__ prec,
    const float* __restrict__ prw, float* __restrict__ scal){
  __shared__ float redS[16], redT[16], redE[16];
  int tid=threadIdx.x, wid=tid>>6, lane=tid&63;
  int b = blockIdx.x>>2, r = blockIdx.x&3;
  const float* sc = scores + (size_t)(b*RNUM+r)*NN;
  const float* pr = prw    + (size_t)(b*RNUM+r)*NN;
  float s0=sc[tid], s1=sc[tid+1024];
  float p0=pr[tid], p1=pr[tid+1024];
  float lE = expf(s0)+expf(s1);
  float lS = prec[b*NN+tid]*p0 + prec[b*NN+tid+1024]*p1;
  float lT = ww[b*NN+tid]*p0   + ww[b*NN+tid+1024]*p1;
  lE=wred_sum(lE); lS=wred_sum(lS); lT=wred_sum(lT);
  if (lane==0){ redE[wid]=lE; redS[wid]=lS; redT[wid]=lT; }
  __syncthreads();
  if (tid==0){
    float S=0.f,T=0.f,E=0.f;
#pragma unroll
    for(int i=0;i<16;i++){ S+=redS[i]; T+=redT[i]; E+=redE[i]; }
    const float* cb = ctr + b*CTRL;
    float c0 = cb[RNUM*WWID + RNUM + r*3 + 0];
    float c1 = cb[RNUM*WWID + RNUM + r*3 + 1];
    float c2 = cb[RNUM*WWID + RNUM + r*3 + 2];
    float mg = fmaxf(c0, fmaxf(c1, c2));
    float e0 = expf(c0-mg), e1 = expf(c1-mg), e2 = expf(c2-mg);
    float inv3 = 1.f/(e0+e1+e2);
    float* s = &scal[(b*RNUM+r)*8];
    s[0]=e0*inv3; s[1]=e1*inv3; s[2]=e2*inv3;
    s[3]=S; s[4]=T; s[5]=1.f/E;
  }
}

// K3: single streaming pass over prev_links, 32 rows x 512 cols per block.
// fwd_part[b,cq,r,i] = sum_{j in cq} L[i,j]*(a_r[j] - ww_i*prw_r[j])
// part[b,tile,r,j]   = sum_{i in tile} L[i,j]*(a_r[i] - ww_j*prw_r[i])
__global__ __launch_bounds__(256) void k3_links(
    const float* __restrict__ L, const float* __restrict__ ww,
    const float* __restrict__ prw, const float* __restrict__ a_arr,
    float* __restrict__ fwd_part, float* __restrict__ part){
  __shared__ float lrow[TI][16];       // {ww, pad x3, a0..a3, p0..p3}
  __shared__ float lcol[4096];         // [wave][r][256 cols] conflict-free
  int tid = threadIdx.x, wid = tid>>6, lane = tid&63;
  int bid = blockIdx.x;
  int b   = bid >> 8;                  // / (TILES*CQ)
  int rem = bid & 255;
  int tile = rem >> 2, cq = rem & 3;
  int i0 = tile*TI, jbase = cq*512;
  if (tid < TI){
    int i = i0 + tid;
    lrow[tid][0] = ww[b*NN + i];
#pragma unroll
    for (int r=0;r<RNUM;r++){
      lrow[tid][4+r] = a_arr[(b*RNUM+r)*NN + i];
      lrow[tid][8+r] = prw[(b*RNUM+r)*NN + i];
    }
  }
  __syncthreads();
  float accf[32];                      // index rr*4 + r
#pragma unroll
  for (int k=0;k<32;k++) accf[k]=0.f;

  for (int c=0;c<2;c++){
    int j0 = jbase + c*256 + lane*4;
    float4 a4[4], p4[4];
#pragma unroll
    for (int r=0;r<4;r++){
      a4[r] = *reinterpret_cast<const float4*>(&a_arr[(b*RNUM+r)*NN + j0]);
      p4[r] = *reinterpret_cast<const float4*>(&prw[(b*RNUM+r)*NN + j0]);
    }
    float4 wwj = *reinterpret_cast<const float4*>(&ww[b*NN + j0]);
    float4 cacc[4];
#pragma unroll
    for (int r=0;r<4;r++){ cacc[r].x=0.f; cacc[r].y=0.f; cacc[r].z=0.f; cacc[r].w=0.f; }

#pragma unroll
    for (int rr=0; rr<8; rr++){
      int lr = wid*8 + rr;
      int i  = i0 + lr;
      float wwi = lrow[lr][0];
      float4 ai4 = *reinterpret_cast<const float4*>(&lrow[lr][4]);
      float4 pi4 = *reinterpret_cast<const float4*>(&lrow[lr][8]);
      float4 L4 = *reinterpret_cast<const float4*>(&L[((size_t)(b*NN + i))*NN + j0]);
#pragma unroll
      for (int r=0;r<4;r++){
        float4 ar = a4[r], pr = p4[r];
        float mx_ = fmaf(-wwi, pr.x, ar.x);
        float my_ = fmaf(-wwi, pr.y, ar.y);
        float mz_ = fmaf(-wwi, pr.z, ar.z);
        float mw_ = fmaf(-wwi, pr.w, ar.w);
        float s = accf[rr*4+r];
        s = fmaf(L4.x, mx_, s); s = fmaf(L4.y, my_, s);
        s = fmaf(L4.z, mz_, s); s = fmaf(L4.w, mw_, s);
        accf[rr*4+r] = s;
        float ai = (r==0)?ai4.x:((r==1)?ai4.y:((r==2)?ai4.z:ai4.w));
        float pi = (r==0)?pi4.x:((r==1)?pi4.y:((r==2)?pi4.z:pi4.w));
        float nx_ = fmaf(-wwj.x, pi, ai);
        float ny_ = fmaf(-wwj.y, pi, ai);
        float nz_ = fmaf(-wwj.z, pi, ai);
        float nw_ = fmaf(-wwj.w, pi, ai);
        cacc[r].x = fmaf(L4.x, nx_, cacc[r].x);
        cacc[r].y = fmaf(L4.y, ny_, cacc[r].y);
        cacc[r].z = fmaf(L4.z, nz_, cacc[r].z);
        cacc[r].w = fmaf(L4.w, nw_, cacc[r].w);
      }
    }
    __syncthreads();   // prior combine-reads done before overwrite
#pragma unroll
    for (int r=0;r<4;r++)
      *reinterpret_cast<float4*>(&lcol[wid*1024 + r*256 + lane*4]) = cacc[r];
    __syncthreads();
    // combine 4 waves; thread (wid,lane) owns (r=wid, cols lane*4..+3)
    float4 v; v.x=0.f; v.y=0.f; v.z=0.f; v.w=0.f;
#pragma unroll
    for (int w=0;w<4;w++){
      float4 t = *reinterpret_cast<const float4*>(&lcol[w*1024 + wid*256 + lane*4]);
      v.x+=t.x; v.y+=t.y; v.z+=t.z; v.w+=t.w;
    }
    *reinterpret_cast<float4*>(
      &part[((size_t)((b*TILES+tile)*RNUM + wid))*NN + jbase + c*256 + lane*4]) = v;
  }

  // packed butterfly: 32 per-lane values -> lane k holds total for value k
#pragma unroll
  for (int k=0;k<32;k++) accf[k] += __shfl_xor(accf[k], 32);
#pragma unroll
  for (int h=16; h>=1; h>>=1){
#pragma unroll
    for (int i=0;i<h;i++){
      float a = accf[i], bb = accf[i+h];
      bool up = (lane & h) != 0;
      float lo = up ? bb : a;
      float hi = up ? a : bb;
      accf[i] = lo + __shfl_xor(hi, h);
    }
  }
  if (lane < 32){
    int k = lane;                       // value index: rr = k>>2, r = k&3
    fwd_part[((size_t)(b*CQ + cq)*RNUM + (k&3))*NN + i0 + wid*8 + (k>>2)] = accf[0];
  }
}

// K45: reduce partials + epilogue -> read_weights (in LDS) -> readout GEMV
// block = (b, r, nb): 256 n's; atomics into zeroed out.
__global__ __launch_bounds__(256) void k45_combine_read(
    const float* __restrict__ part, const float* __restrict__ fwd_part,
    const float* __restrict__ scores, const float* __restrict__ scal,
    const float* __restrict__ ww, const float* __restrict__ prec,
    const float* __restrict__ prw, const float* __restrict__ Ldiag,
    const float* __restrict__ mem, float* __restrict__ out){
  __shared__ float rwl[256];
  int tid = threadIdx.x;
  int b = blockIdx.x >> 5, rem = blockIdx.x & 31;
  int r = rem >> 3, nb = rem & 7;
  int n = nb*256 + tid;
  const float* s = &scal[(b*RNUM+r)*8];
  float g0=s[0], g1=s[1], g2=s[2], S=s[3], T=s[4], inv=s[5];
  const float* pp = part + ((size_t)(b*TILES)*RNUM + r)*NN + n;
  float b0=0.f,b1=0.f,b2=0.f,b3=0.f;
  for (int t=0;t<TILES;t+=4){
    b0 += pp[(size_t)(t+0)*RNUM*NN];
    b1 += pp[(size_t)(t+1)*RNUM*NN];
    b2 += pp[(size_t)(t+2)*RNUM*NN];
    b3 += pp[(size_t)(t+3)*RNUM*NN];
  }
  float bsum = (b0+b1)+(b2+b3);
  float fsum = 0.f;
#pragma unroll
  for (int cq=0;cq<CQ;cq++)
    fsum += fwd_part[((size_t)(b*CQ + cq)*RNUM + r)*NN + n];
  float wwn = ww[b*NN+n], pn = prec[b*NN+n], prn = prw[(b*RNUM+r)*NN+n];
  float Lnn = Ldiag[b*NN+n];
  float diag = (fmaf(-2.f*wwn, Lnn, Lnn) + wwn*pn) * prn;
  float fwd = fsum + wwn*S - diag;
  float bwd = bsum + pn*T - diag;
  float content = expf(scores[(b*RNUM+r)*NN+n]) * inv;
  rwl[tid] = g0*fwd + g1*bwd + g2*content;
  __syncthreads();
  // readout: wave w handles n-slice [w*64, w*64+64); mem is L3-warm after K1
  int w = tid>>6, lane = tid&63;
  float acc = 0.f;
  const float* mp = mem + ((size_t)(b*NN + nb*256 + w*64))*WWID + lane;
#pragma unroll 4
  for (int q=0; q<64; q++)
    acc = fmaf(mp[(size_t)q*WWID], rwl[w*64+q], acc);
  atomicAdd(&out[(b*RNUM+r)*WWID + lane], acc);
}

extern "C" void kernel_launch(void* const* d_in, const int* in_sizes, int n_in,
                              void* d_out, int out_size, void* d_ws, size_t ws_size,
                              hipStream_t stream){
  const float* mem  = (const float*)d_in[0];
  const float* ctr  = (const float*)d_in[1];
  const float* ww   = (const float*)d_in[2];
  const float* L    = (const float*)d_in[3];
  const float* prec = (const float*)d_in[4];
  const float* prw  = (const float*)d_in[5];
  float* out = (float*)d_out;
  float* w = (float*)d_ws;

  float* scores   = w;                        // B*R*N
  float* a_arr    = scores + BB*RNUM*NN;      // B*R*N
  float* Ldiag    = a_arr + BB*RNUM*NN;       // B*N
  float* scal     = Ldiag + BB*NN;            // 256
  float* fwd_part = scal + 256;               // B*CQ*R*N
  float* part     = fwd_part + BB*CQ*RNUM*NN; // B*TILES*R*N

  hipMemsetAsync(out, 0, (size_t)BB*RNUM*WWID*sizeof(float), stream);
  k1_prep<<<BB*NN/4, 256, 0, stream>>>(mem, ctr, ww, prw, L, scores, a_arr, Ldiag);
  k2_head<<<BB*RNUM, 1024, 0, stream>>>(ctr, scores, ww, prec, prw, scal);
  k3_links<<<BB*TILES*CQ, 256, 0, stream>>>(L, ww, prw, a_arr, fwd_part, part);
  k45_combine_read<<<BB*RNUM*8, 256, 0, stream>>>(part, fwd_part, scores, scal,
                                                  ww, prec, prw, Ldiag, mem, out);
}

// Round 8
// 244.463 us; speedup vs baseline: 1.0936x; 1.0226x over previous
//
#include <hip/hip_runtime.h>
#include <hip/hip_bf16.h>
#include <math.h>

#define BB 8
#define NN 2048
#define WWID 64
#define RNUM 4
#define CTRL 272      // R*W + R + R*3
#define EPSF 1e-8f
#define TI 32         // rows per K3 block
#define TILES 64      // NN/TI
#define CQ 4          // column quarters in K3 (512 cols each)
#define K3BLKS (BB*TILES*CQ)   // 2048

__device__ __forceinline__ float wred_sum(float v){
#pragma unroll
  for (int m=1;m<64;m<<=1) v += __shfl_xor(v,m);
  return v;
}
__device__ __forceinline__ unsigned short f2bf(float f){
  __hip_bfloat16 h = __float2bfloat16(f);
  return *reinterpret_cast<unsigned short*>(&h);
}
__device__ __forceinline__ float bf2f(unsigned short u){
  return __uint_as_float(((unsigned)u) << 16);
}

// K1: per (b,n) wave: scores[b,r,n] (beta folded in), a[b,r,n]=(1-ww)*prw,
//     Ldiag[b,n] = L[b,n,n].  Block 0 additionally zeroes out[].
__global__ __launch_bounds__(256) void k1_prep(
    const float* __restrict__ mem, const float* __restrict__ ctr,
    const float* __restrict__ ww, const float* __restrict__ prw,
    const float* __restrict__ L,
    float* __restrict__ scores, float* __restrict__ a_arr,
    float* __restrict__ Ldiag, float* __restrict__ out){
  int tid = threadIdx.x;
  if (blockIdx.x == 0){
    float4 z = {0.f,0.f,0.f,0.f};
    reinterpret_cast<float4*>(out)[tid]       = z;
    reinterpret_cast<float4*>(out)[tid + 256] = z;
  }
  int wid = tid >> 6, lane = tid & 63;
  int g = blockIdx.x * 4 + wid;        // wave id == (b,n)
  int b = g >> 11, n = g & (NN-1);
  float m = mem[((size_t)(b*NN + n))*WWID + lane];
  const float* cb = ctr + b*CTRL;
  float k0 = cb[0*WWID+lane], k1 = cb[1*WWID+lane];
  float k2 = cb[2*WWID+lane], k3 = cb[3*WWID+lane];
  float s0 = m*m;
  float d0 = m*k0, d1 = m*k1, d2 = m*k2, d3 = m*k3;
  float q0 = k0*k0, q1 = k1*k1, q2 = k2*k2, q3 = k3*k3;
#pragma unroll
  for (int t=1;t<64;t<<=1){
    s0 += __shfl_xor(s0,t);
    d0 += __shfl_xor(d0,t); d1 += __shfl_xor(d1,t);
    d2 += __shfl_xor(d2,t); d3 += __shfl_xor(d3,t);
    q0 += __shfl_xor(q0,t); q1 += __shfl_xor(q1,t);
    q2 += __shfl_xor(q2,t); q3 += __shfl_xor(q3,t);
  }
  if (lane==0){
    float mn = sqrtf(s0);
    float be[4];
#pragma unroll
    for (int r=0;r<4;r++){
      float x = cb[RNUM*WWID + r];
      be[r] = 1.f + (x > 20.f ? x : log1pf(expf(x)));
    }
    scores[(b*RNUM+0)*NN+n] = d0*be[0]/(sqrtf(q0)*mn + EPSF);
    scores[(b*RNUM+1)*NN+n] = d1*be[1]/(sqrtf(q1)*mn + EPSF);
    scores[(b*RNUM+2)*NN+n] = d2*be[2]/(sqrtf(q2)*mn + EPSF);
    scores[(b*RNUM+3)*NN+n] = d3*be[3]/(sqrtf(q3)*mn + EPSF);
    Ldiag[b*NN+n] = L[((size_t)(b*NN+n))*NN + n];
  }
  if (lane < RNUM){
    int r = lane;
    a_arr[(b*RNUM+r)*NN+n] = (1.f - ww[b*NN+n]) * prw[(b*RNUM+r)*NN+n];
  }
}

// K23: fat kernel.  Blocks [0, K3BLKS): streaming pass over prev_links.
//      Blocks [K3BLKS, K3BLKS+32): per-(b,r) scalar reductions (old K2).
// fwd_part[b,cq,r,i] = sum_{j in cq} L[i,j]*(a_r[j] - ww_i*prw_r[j])
// part[b,tile,r,j]   = sum_{i in tile} L[i,j]*(a_r[i] - ww_j*prw_r[i])  (bf16)
__global__ __launch_bounds__(256) void k23_links_head(
    const float* __restrict__ L, const float* __restrict__ ww,
    const float* __restrict__ prw, const float* __restrict__ a_arr,
    const float* __restrict__ ctr, const float* __restrict__ scores,
    const float* __restrict__ prec,
    float* __restrict__ fwd_part, unsigned short* __restrict__ part,
    float* __restrict__ scal){
  __shared__ float lrow[TI][16];       // {ww, pad x3, a0..a3, p0..p3}
  __shared__ float lcol[4096];         // [wave][r][256 cols] conflict-free
  __shared__ float red[3][4];
  int tid = threadIdx.x, wid = tid>>6, lane = tid&63;
  int bid = blockIdx.x;

  if (bid >= K3BLKS){
    // ---- K2 path: per (b,r) scalars {g0,g1,g2,S,T,invE} ----
    int idx = bid - K3BLKS;
    int b = idx >> 2, r = idx & 3;
    const float* sc = scores + (size_t)(b*RNUM+r)*NN;
    const float* pr = prw    + (size_t)(b*RNUM+r)*NN;
    float lE=0.f, lS=0.f, lT=0.f;
#pragma unroll
    for (int k=0;k<8;k++){
      int n = tid + k*256;
      float p = pr[n];
      lE += expf(sc[n]);
      lS = fmaf(prec[b*NN+n], p, lS);
      lT = fmaf(ww[b*NN+n],   p, lT);
    }
    lE=wred_sum(lE); lS=wred_sum(lS); lT=wred_sum(lT);
    if (lane==0){ red[0][wid]=lE; red[1][wid]=lS; red[2][wid]=lT; }
    __syncthreads();
    if (tid==0){
      float E = red[0][0]+red[0][1]+red[0][2]+red[0][3];
      float S = red[1][0]+red[1][1]+red[1][2]+red[1][3];
      float T = red[2][0]+red[2][1]+red[2][2]+red[2][3];
      const float* cb = ctr + b*CTRL;
      float c0 = cb[RNUM*WWID + RNUM + r*3 + 0];
      float c1 = cb[RNUM*WWID + RNUM + r*3 + 1];
      float c2 = cb[RNUM*WWID + RNUM + r*3 + 2];
      float mg = fmaxf(c0, fmaxf(c1, c2));
      float e0 = expf(c0-mg), e1 = expf(c1-mg), e2 = expf(c2-mg);
      float inv3 = 1.f/(e0+e1+e2);
      float* s = &scal[(b*RNUM+r)*8];
      s[0]=e0*inv3; s[1]=e1*inv3; s[2]=e2*inv3;
      s[3]=S; s[4]=T; s[5]=1.f/E;
    }
    return;
  }

  // ---- K3 path ----
  int b   = bid >> 8;                  // / (TILES*CQ)
  int rem = bid & 255;
  int tile = rem >> 2, cq = rem & 3;
  int i0 = tile*TI, jbase = cq*512;
  if (tid < TI){
    int i = i0 + tid;
    lrow[tid][0] = ww[b*NN + i];
#pragma unroll
    for (int r=0;r<RNUM;r++){
      lrow[tid][4+r] = a_arr[(b*RNUM+r)*NN + i];
      lrow[tid][8+r] = prw[(b*RNUM+r)*NN + i];
    }
  }
  __syncthreads();
  float accf[32];                      // index rr*4 + r
#pragma unroll
  for (int k=0;k<32;k++) accf[k]=0.f;

  for (int c=0;c<2;c++){
    int j0 = jbase + c*256 + lane*4;
    float4 a4[4], p4[4];
#pragma unroll
    for (int r=0;r<4;r++){
      a4[r] = *reinterpret_cast<const float4*>(&a_arr[(b*RNUM+r)*NN + j0]);
      p4[r] = *reinterpret_cast<const float4*>(&prw[(b*RNUM+r)*NN + j0]);
    }
    float4 wwj = *reinterpret_cast<const float4*>(&ww[b*NN + j0]);
    float4 cacc[4];
#pragma unroll
    for (int r=0;r<4;r++){ cacc[r].x=0.f; cacc[r].y=0.f; cacc[r].z=0.f; cacc[r].w=0.f; }

#pragma unroll
    for (int rr=0; rr<8; rr++){
      int lr = wid*8 + rr;
      int i  = i0 + lr;
      float wwi = lrow[lr][0];
      float4 ai4 = *reinterpret_cast<const float4*>(&lrow[lr][4]);
      float4 pi4 = *reinterpret_cast<const float4*>(&lrow[lr][8]);
      float4 L4 = *reinterpret_cast<const float4*>(&L[((size_t)(b*NN + i))*NN + j0]);
#pragma unroll
      for (int r=0;r<4;r++){
        float4 ar = a4[r], pr = p4[r];
        float mx_ = fmaf(-wwi, pr.x, ar.x);
        float my_ = fmaf(-wwi, pr.y, ar.y);
        float mz_ = fmaf(-wwi, pr.z, ar.z);
        float mw_ = fmaf(-wwi, pr.w, ar.w);
        float s = accf[rr*4+r];
        s = fmaf(L4.x, mx_, s); s = fmaf(L4.y, my_, s);
        s = fmaf(L4.z, mz_, s); s = fmaf(L4.w, mw_, s);
        accf[rr*4+r] = s;
        float ai = (r==0)?ai4.x:((r==1)?ai4.y:((r==2)?ai4.z:ai4.w));
        float pi = (r==0)?pi4.x:((r==1)?pi4.y:((r==2)?pi4.z:pi4.w));
        float nx_ = fmaf(-wwj.x, pi, ai);
        float ny_ = fmaf(-wwj.y, pi, ai);
        float nz_ = fmaf(-wwj.z, pi, ai);
        float nw_ = fmaf(-wwj.w, pi, ai);
        cacc[r].x = fmaf(L4.x, nx_, cacc[r].x);
        cacc[r].y = fmaf(L4.y, ny_, cacc[r].y);
        cacc[r].z = fmaf(L4.z, nz_, cacc[r].z);
        cacc[r].w = fmaf(L4.w, nw_, cacc[r].w);
      }
    }
    __syncthreads();   // prior combine-reads done before overwrite
#pragma unroll
    for (int r=0;r<4;r++)
      *reinterpret_cast<float4*>(&lcol[wid*1024 + r*256 + lane*4]) = cacc[r];
    __syncthreads();
    // combine 4 waves; thread (wid,lane) owns (r=wid, cols lane*4..+3)
    float4 v; v.x=0.f; v.y=0.f; v.z=0.f; v.w=0.f;
#pragma unroll
    for (int w=0;w<4;w++){
      float4 t = *reinterpret_cast<const float4*>(&lcol[w*1024 + wid*256 + lane*4]);
      v.x+=t.x; v.y+=t.y; v.z+=t.z; v.w+=t.w;
    }
    ushort4 sv;
    sv.x = f2bf(v.x); sv.y = f2bf(v.y); sv.z = f2bf(v.z); sv.w = f2bf(v.w);
    *reinterpret_cast<ushort4*>(
      &part[((size_t)((b*TILES+tile)*RNUM + wid))*NN + jbase + c*256 + lane*4]) = sv;
  }

  // packed butterfly: 32 per-lane values -> lane k holds total for value k
#pragma unroll
  for (int k=0;k<32;k++) accf[k] += __shfl_xor(accf[k], 32);
#pragma unroll
  for (int h=16; h>=1; h>>=1){
#pragma unroll
    for (int i=0;i<h;i++){
      float a = accf[i], bb = accf[i+h];
      bool up = (lane & h) != 0;
      float lo = up ? bb : a;
      float hi = up ? a : bb;
      accf[i] = lo + __shfl_xor(hi, h);
    }
  }
  if (lane < 32){
    int k = lane;                       // value index: rr = k>>2, r = k&3
    fwd_part[((size_t)(b*CQ + cq)*RNUM + (k&3))*NN + i0 + wid*8 + (k>>2)] = accf[0];
  }
}

// K45: reduce partials + epilogue -> read_weights (in LDS) -> readout GEMV
// block = (b, r, nb): 256 n's; atomics into out (zeroed by K1).
__global__ __launch_bounds__(256) void k45_combine_read(
    const unsigned short* __restrict__ part, const float* __restrict__ fwd_part,
    const float* __restrict__ scores, const float* __restrict__ scal,
    const float* __restrict__ ww, const float* __restrict__ prec,
    const float* __restrict__ prw, const float* __restrict__ Ldiag,
    const float* __restrict__ mem, float* __restrict__ out){
  __shared__ float rwl[256];
  int tid = threadIdx.x;
  int b = blockIdx.x >> 5, rem = blockIdx.x & 31;
  int r = rem >> 3, nb = rem & 7;
  int n = nb*256 + tid;
  const float* s = &scal[(b*RNUM+r)*8];
  float g0=s[0], g1=s[1], g2=s[2], S=s[3], T=s[4], inv=s[5];
  const unsigned short* pp = part + ((size_t)(b*TILES)*RNUM + r)*NN + n;
  float b0=0.f,b1=0.f,b2=0.f,b3=0.f;
  for (int t=0;t<TILES;t+=4){
    b0 += bf2f(pp[(size_t)(t+0)*RNUM*NN]);
    b1 += bf2f(pp[(size_t)(t+1)*RNUM*NN]);
    b2 += bf2f(pp[(size_t)(t+2)*RNUM*NN]);
    b3 += bf2f(pp[(size_t)(t+3)*RNUM*NN]);
  }
  float bsum = (b0+b1)+(b2+b3);
  float fsum = 0.f;
#pragma unroll
  for (int cq=0;cq<CQ;cq++)
    fsum += fwd_part[((size_t)(b*CQ + cq)*RNUM + r)*NN + n];
  float wwn = ww[b*NN+n], pn = prec[b*NN+n], prn = prw[(b*RNUM+r)*NN+n];
  float Lnn = Ldiag[b*NN+n];
  float diag = (fmaf(-2.f*wwn, Lnn, Lnn) + wwn*pn) * prn;
  float fwd = fsum + wwn*S - diag;
  float bwd = bsum + pn*T - diag;
  float content = expf(scores[(b*RNUM+r)*NN+n]) * inv;
  rwl[tid] = g0*fwd + g1*bwd + g2*content;
  __syncthreads();
  // readout: wave w handles n-slice [w*64, w*64+64)
  int w = tid>>6, lane = tid&63;
  float acc = 0.f;
  const float* mp = mem + ((size_t)(b*NN + nb*256 + w*64))*WWID + lane;
#pragma unroll 4
  for (int q=0; q<64; q++)
    acc = fmaf(mp[(size_t)q*WWID], rwl[w*64+q], acc);
  atomicAdd(&out[(b*RNUM+r)*WWID + lane], acc);
}

extern "C" void kernel_launch(void* const* d_in, const int* in_sizes, int n_in,
                              void* d_out, int out_size, void* d_ws, size_t ws_size,
                              hipStream_t stream){
  const float* mem  = (const float*)d_in[0];
  const float* ctr  = (const float*)d_in[1];
  const float* ww   = (const float*)d_in[2];
  const float* L    = (const float*)d_in[3];
  const float* prec = (const float*)d_in[4];
  const float* prw  = (const float*)d_in[5];
  float* out = (float*)d_out;
  float* w = (float*)d_ws;

  float* scores   = w;                        // B*R*N
  float* a_arr    = scores + BB*RNUM*NN;      // B*R*N
  float* Ldiag    = a_arr + BB*RNUM*NN;       // B*N
  float* scal     = Ldiag + BB*NN;            // 256
  float* fwd_part = scal + 256;               // B*CQ*R*N
  unsigned short* part = (unsigned short*)(fwd_part + BB*CQ*RNUM*NN); // B*TILES*R*N bf16

  k1_prep<<<BB*NN/4, 256, 0, stream>>>(mem, ctr, ww, prw, L, scores, a_arr, Ldiag, out);
  k23_links_head<<<K3BLKS + BB*RNUM, 256, 0, stream>>>(L, ww, prw, a_arr, ctr, scores,
                                                       prec, fwd_part, part, scal);
  k45_combine_read<<<BB*RNUM*8, 256, 0, stream>>>(part, fwd_part, scores, scal,
                                                  ww, prec, prw, Ldiag, mem, out);
}